// Round 8
// baseline (440.939 us; speedup 1.0000x reference)
//
#include <hip/hip_runtime.h>
#include <hip/hip_bf16.h>

#define BB 2
#define NN 2048
#define DD 128
#define BN (BB*NN)
#define CAP 128
#define TD 16
#define INV_SQRT_D 0.08838834764831845f

typedef __attribute__((ext_vector_type(8))) short short8;
typedef __attribute__((ext_vector_type(4))) float f32x4;

__device__ __forceinline__ float bf2f(short u) {
    union { unsigned int i; float f; } t;
    t.i = ((unsigned int)(unsigned short)u) << 16;
    return t.f;
}

// ---------------------------------------------------------------------------
// LDS-tiled CSR build of e_t[b,dst,src] = edge[b,src,dst]*A[b,src,dst].
// Interleaved int2 {src_row, ee_bits}; FULL CAP rows, pads = {0, 0.0f}.
// (real edges have ee >= 0.1, so ee>0 is the validity mask downstream)
// ---------------------------------------------------------------------------
__global__ __launch_bounds__(256) void build_csr(
    const float* __restrict__ A,
    const float* __restrict__ edge,
    int2* __restrict__ csr)
{
    __shared__ int   cnt[TD];
    __shared__ int   csh[TD][CAP];
    __shared__ float esh[TD][CAP];

    int bid  = blockIdx.x;
    int b    = bid / (NN / TD);
    int dst0 = (bid % (NN / TD)) * TD;
    int tid  = threadIdx.x;

    if (tid < TD) cnt[tid] = 0;
    __syncthreads();

    int srcOff = tid >> 2;
    int dOff   = (tid & 3) * 4;
    const size_t base = (size_t)b * NN * NN + dst0 + dOff;

#pragma unroll 2
    for (int s0 = 0; s0 < NN; s0 += 64) {
        int src = s0 + srcOff;
        float4 a4 = *(const float4*)&A[base + (size_t)src * NN];
        float4 e4 = *(const float4*)&edge[base + (size_t)src * NN];
        int gsrc = b * NN + src;
        float av[4] = {a4.x, a4.y, a4.z, a4.w};
        float ev[4] = {e4.x, e4.y, e4.z, e4.w};
#pragma unroll
        for (int u = 0; u < 4; u++) {
            if (av[u] != 0.f) {
                int d = dOff + u;
                int slot = atomicAdd(&cnt[d], 1);
                if (slot < CAP) { csh[d][slot] = gsrc; esh[d][slot] = ev[u] * av[u]; }
            }
        }
    }
    __syncthreads();

    for (int idx = tid; idx < TD * CAP; idx += 256) {
        int d = idx / CAP, i = idx % CAP;
        int c = min(cnt[d], CAP);
        int2 val;
        if (i < c) { val.x = csh[d][i]; val.y = __float_as_int(esh[d][i]); }
        else       { val.x = 0;         val.y = 0; }
        csr[(size_t)(b * NN + dst0 + d) * CAP + i] = val;
    }
}

// ---------------------------------------------------------------------------
// Weight prep: Wt[n][k] = W*[k][n] as bf16, cols concat [q | k | v | skip].
// ---------------------------------------------------------------------------
__global__ __launch_bounds__(128) void prep_weights(
    const float* __restrict__ Wq, const float* __restrict__ Wk,
    const float* __restrict__ Wv, const float* __restrict__ Ws,
    __hip_bfloat16* __restrict__ Wt, int HD)
{
    int n = blockIdx.x;
    int t = threadIdx.x;
    const float* src; int ld; int col;
    if      (n < HD)     { src = Wq; col = n;          ld = HD; }
    else if (n < 2*HD)   { src = Wk; col = n - HD;     ld = HD; }
    else if (n < 3*HD)   { src = Wv; col = n - 2*HD;   ld = HD; }
    else                 { src = Ws; col = n - 3*HD;   ld = DD; }
    Wt[(size_t)n * DD + t] = __float2bfloat16(src[(size_t)t * ld + col]);
}

// ---------------------------------------------------------------------------
// Layer-0 projection (FIN=1, rank-1). q/skip fp32; k/v bf16.
// ---------------------------------------------------------------------------
__global__ __launch_bounds__(128) void proj_l0(
    const float* __restrict__ x,
    const float* __restrict__ Wq, const float* __restrict__ Wk,
    const float* __restrict__ Wv, const float* __restrict__ Ws,
    float* __restrict__ q, __hip_bfloat16* __restrict__ kb,
    __hip_bfloat16* __restrict__ vb, float* __restrict__ skip)
{
    __shared__ float xs[16];
    int row0 = blockIdx.x * 16;
    int col  = blockIdx.y * 128 + threadIdx.x;
    if (threadIdx.x < 16) xs[threadIdx.x] = x[row0 + threadIdx.x];
    __syncthreads();

    if (col < DD) {
        float wf = Wq[col];
#pragma unroll
        for (int r = 0; r < 16; r++) q[(size_t)(row0 + r) * DD + col] = xs[r] * wf;
    } else if (col < 2*DD) {
        float wf = Wk[col - DD];
#pragma unroll
        for (int r = 0; r < 16; r++) kb[(size_t)(row0 + r) * DD + col - DD] = __float2bfloat16(xs[r] * wf);
    } else if (col < 3*DD) {
        float wf = Wv[col - 2*DD];
#pragma unroll
        for (int r = 0; r < 16; r++) vb[(size_t)(row0 + r) * DD + col - 2*DD] = __float2bfloat16(xs[r] * wf);
    } else {
        float wf = Ws[col - 3*DD];
#pragma unroll
        for (int r = 0; r < 16; r++) skip[(size_t)(row0 + r) * DD + col - 3*DD] = xs[r] * wf;
    }
}

// ---------------------------------------------------------------------------
// MFMA bf16 projection. q/skip fp32 out; k/v bf16 out.
// ---------------------------------------------------------------------------
template<int HD>
__global__ __launch_bounds__(256) void proj_mfma(
    const __hip_bfloat16* __restrict__ xb,
    const __hip_bfloat16* __restrict__ Wt,
    float* __restrict__ q, __hip_bfloat16* __restrict__ kb,
    __hip_bfloat16* __restrict__ vb, float* __restrict__ skip)
{
    int wid  = threadIdx.x >> 6, lane = threadIdx.x & 63;
    int row0 = blockIdx.x * 64 + wid * 16;
    int n0   = blockIdx.y * 64;
    int m    = lane & 15, quad = lane >> 4;

    f32x4 acc[4] = {f32x4{0,0,0,0}, f32x4{0,0,0,0}, f32x4{0,0,0,0}, f32x4{0,0,0,0}};
    const short8* ap = (const short8*)&xb[(size_t)(row0 + m) * DD + quad * 8];
#pragma unroll
    for (int ks = 0; ks < 4; ks++) {
        short8 a = ap[ks * 4];
#pragma unroll
        for (int t = 0; t < 4; t++) {
            const short8* bp = (const short8*)&Wt[(size_t)(n0 + t * 16 + m) * DD + ks * 32 + quad * 8];
            acc[t] = __builtin_amdgcn_mfma_f32_16x16x32_bf16(a, *bp, acc[t], 0, 0, 0);
        }
    }

    if (n0 < HD) {
        int lc0 = n0;
#pragma unroll
        for (int t = 0; t < 4; t++)
#pragma unroll
            for (int r = 0; r < 4; r++)
                q[(size_t)(row0 + quad * 4 + r) * HD + lc0 + t * 16 + m] = acc[t][r];
    } else if (n0 < 2 * HD) {
        int lc0 = n0 - HD;
#pragma unroll
        for (int t = 0; t < 4; t++)
#pragma unroll
            for (int r = 0; r < 4; r++)
                kb[(size_t)(row0 + quad * 4 + r) * HD + lc0 + t * 16 + m] = __float2bfloat16(acc[t][r]);
    } else if (n0 < 3 * HD) {
        int lc0 = n0 - 2 * HD;
#pragma unroll
        for (int t = 0; t < 4; t++)
#pragma unroll
            for (int r = 0; r < 4; r++)
                vb[(size_t)(row0 + quad * 4 + r) * HD + lc0 + t * 16 + m] = __float2bfloat16(acc[t][r]);
    } else {
        int lc0 = n0 - 3 * HD;
#pragma unroll
        for (int t = 0; t < 4; t++)
#pragma unroll
            for (int r = 0; r < 4; r++)
                skip[(size_t)(row0 + quad * 4 + r) * DD + lc0 + t * 16 + m] = acc[t][r];
    }
}

// ---------------------------------------------------------------------------
// Sparse attention v4: STATIC stream, one block (4 waves) per dst row.
// All CAP=128 slots processed unconditionally; pad slots have ee==0 -> a=0
// and gather row 0 (hot line). No deg read, no branches, no in-loop
// cross-lane traffic except the 3-step score reduce over 8 s-lanes.
// Wave wid, group i (i<4): edge slot = i*32 + wid*8 + sub.
// Lane: sub=lane>>3 (edge in group), s=lane&7 (16-ch slice).
// H=1: all 4 groups' gathers in flight at once; H=2: 2 rounds of 2.
// ---------------------------------------------------------------------------
template<int H, bool MEANH, bool LNRELU, bool OUTBF>
__global__ __launch_bounds__(256) void attn_kernel(
    const float* __restrict__ q, const __hip_bfloat16* __restrict__ kb,
    const __hip_bfloat16* __restrict__ vb, const float* __restrict__ skip,
    const int2* __restrict__ csr, const float* __restrict__ We,
    void* __restrict__ outv)
{
    const int HD = H * DD;
    constexpr int UNR = (H == 1) ? 4 : 2;
    int tid  = threadIdx.x;
    int wid  = tid >> 6;
    int lane = tid & 63;
    int row  = blockIdx.x;
    int sub  = lane >> 3;
    int s    = lane & 7;

    __shared__ float red[4][H][DD];
    __shared__ float lred[4][H], ewred[4][H];

    // CSR slots for this wave's 4 groups (issued immediately, no predicates)
    int jb[4]; float eb[4];
#pragma unroll
    for (int i = 0; i < 4; i++) {
        int2 ce = csr[(size_t)row * CAP + i * 32 + wid * 8 + sub];
        jb[i] = ce.x; eb[i] = __int_as_float(ce.y);
    }

    // q fragment (16 ch/lane, dep on s only) + qe[h] = q . We[h]
    float qh[H][16];
    float qeI[H];
#pragma unroll
    for (int h = 0; h < H; h++) {
        const float* qp = &q[(size_t)row * HD + h * DD + s * 16];
        const float* wp = &We[h * DD + s * 16];
        float pe = 0.f;
#pragma unroll
        for (int t = 0; t < 16; t++) { qh[h][t] = qp[t]; pe += qp[t] * wp[t]; }
        pe += __shfl_xor(pe, 1); pe += __shfl_xor(pe, 2); pe += __shfl_xor(pe, 4);
        qeI[h] = pe * INV_SQRT_D;
    }

    float l_acc[H], ew_acc[H], acc[H][16];
#pragma unroll
    for (int h = 0; h < H; h++) {
        l_acc[h] = 0.f; ew_acc[h] = 0.f;
#pragma unroll
        for (int t = 0; t < 16; t++) acc[h][t] = 0.f;
    }

#pragma unroll
    for (int r0 = 0; r0 < 4; r0 += UNR) {
        // issue ALL gathers for UNR groups first (independent)
        short8 kf[UNR][H][2], vf[UNR][H][2];
#pragma unroll
        for (int u = 0; u < UNR; u++) {
            int j = jb[r0 + u];
#pragma unroll
            for (int h = 0; h < H; h++) {
                const short8* kp = (const short8*)&kb[(size_t)j * HD + h * DD + s * 16];
                const short8* vp = (const short8*)&vb[(size_t)j * HD + h * DD + s * 16];
                kf[u][h][0] = kp[0]; kf[u][h][1] = kp[1];
                vf[u][h][0] = vp[0]; vf[u][h][1] = vp[1];
            }
        }
        // compute
#pragma unroll
        for (int u = 0; u < UNR; u++) {
            float ee = eb[r0 + u];
#pragma unroll
            for (int h = 0; h < H; h++) {
                float p = 0.f;
#pragma unroll
                for (int t = 0; t < 8; t++) p += qh[h][t]     * bf2f(kf[u][h][0][t]);
#pragma unroll
                for (int t = 0; t < 8; t++) p += qh[h][8 + t] * bf2f(kf[u][h][1][t]);
                p += __shfl_xor(p, 1); p += __shfl_xor(p, 2); p += __shfl_xor(p, 4);
                float sc = p * INV_SQRT_D + qeI[h] * ee;
                float a  = (ee > 0.f) ? __expf(fminf(sc, 60.f)) : 0.f;
                l_acc[h]  += a;
                ew_acc[h] += a * ee;
#pragma unroll
                for (int t = 0; t < 8; t++) acc[h][t]     += a * bf2f(vf[u][h][0][t]);
#pragma unroll
                for (int t = 0; t < 8; t++) acc[h][8 + t] += a * bf2f(vf[u][h][1][t]);
            }
        }
    }

    // one-time butterfly over sub bits {8,16,32}
#pragma unroll
    for (int h = 0; h < H; h++) {
#pragma unroll
        for (int t = 0; t < 16; t++) {
            float x = acc[h][t];
            x += __shfl_xor(x, 8); x += __shfl_xor(x, 16); x += __shfl_xor(x, 32);
            acc[h][t] = x;
        }
        float l = l_acc[h];
        l += __shfl_xor(l, 8); l += __shfl_xor(l, 16); l += __shfl_xor(l, 32);
        l_acc[h] = l;
        float ew = ew_acc[h];
        ew += __shfl_xor(ew, 8); ew += __shfl_xor(ew, 16); ew += __shfl_xor(ew, 32);
        ew_acc[h] = ew;
    }

    // per-wave partials -> LDS (float4 stores; lanes 0..7)
    if (lane < 8) {
#pragma unroll
        for (int h = 0; h < H; h++)
#pragma unroll
            for (int t4 = 0; t4 < 4; t4++) {
                f32x4 v4 = { acc[h][t4*4], acc[h][t4*4+1], acc[h][t4*4+2], acc[h][t4*4+3] };
                *(f32x4*)&red[wid][h][lane * 16 + t4 * 4] = v4;
            }
    }
    if (lane == 0) {
#pragma unroll
        for (int h = 0; h < H; h++) { lred[wid][h] = l_acc[h]; ewred[wid][h] = ew_acc[h]; }
    }
    __syncthreads();

    // epilogue on wave 0 (2 ch/lane)
    if (wid == 0) {
        int c0 = lane * 2;
        float rh[H][2];
#pragma unroll
        for (int h = 0; h < H; h++) {
            float a0 = 0.f, a1 = 0.f, l = 0.f, ew = 0.f;
#pragma unroll
            for (int w = 0; w < 4; w++) {
                a0 += red[w][h][c0];
                a1 += red[w][h][c0 + 1];
                l  += lred[w][h];
                ew += ewred[w][h];
            }
            float invZ = (l > 0.f) ? 1.f / l : 0.f;
            rh[h][0] = (a0 + ew * We[h * DD + c0])     * invZ;
            rh[h][1] = (a1 + ew * We[h * DD + c0 + 1]) * invZ;
        }
        float r0, r1;
        if constexpr (MEANH) {
            r0 = 0.5f * (rh[0][0] + rh[H - 1][0]);
            r1 = 0.5f * (rh[0][1] + rh[H - 1][1]);
        } else {
            r0 = rh[0][0]; r1 = rh[0][1];
        }
        float2 sk = *(const float2*)&skip[(size_t)row * DD + c0];
        r0 += sk.x; r1 += sk.y;

        if constexpr (LNRELU) {
            float sum = r0 + r1, sq = r0 * r0 + r1 * r1;
#pragma unroll
            for (int off = 32; off; off >>= 1) { sum += __shfl_xor(sum, off); sq += __shfl_xor(sq, off); }
            float mu  = sum * (1.f / DD);
            float var = sq * (1.f / DD) - mu * mu;
            float rs  = rsqrtf(var + 1e-5f);
            r0 = fmaxf((r0 - mu) * rs, 0.f);
            r1 = fmaxf((r1 - mu) * rs, 0.f);
        }

        if constexpr (OUTBF) {
            __hip_bfloat16* ob = (__hip_bfloat16*)outv;
            __hip_bfloat162 o;
            o.x = __float2bfloat16(r0);
            o.y = __float2bfloat16(r1);
            *(__hip_bfloat162*)&ob[(size_t)row * DD + c0] = o;
        } else {
            float2 res; res.x = r0; res.y = r1;
            *(float2*)&((float*)outv)[(size_t)row * DD + c0] = res;
        }
    }
}

// ---------------------------------------------------------------------------
extern "C" void kernel_launch(void* const* d_in, const int* in_sizes, int n_in,
                              void* d_out, int out_size, void* d_ws, size_t ws_size,
                              hipStream_t stream)
{
    const float* node = (const float*)d_in[0];
    const float* edge = (const float*)d_in[1];
    const float* A    = (const float*)d_in[2];
    const float* Wq[3] = {(const float*)d_in[3],  (const float*)d_in[8],  (const float*)d_in[13]};
    const float* Wk[3] = {(const float*)d_in[4],  (const float*)d_in[9],  (const float*)d_in[14]};
    const float* Wv[3] = {(const float*)d_in[5],  (const float*)d_in[10], (const float*)d_in[15]};
    const float* We[3] = {(const float*)d_in[6],  (const float*)d_in[11], (const float*)d_in[16]};
    const float* Ws[3] = {(const float*)d_in[7],  (const float*)d_in[12], (const float*)d_in[17]};

    // workspace carve
    char* p = (char*)d_ws;
    float*          qbuf = (float*)p;          p += (size_t)BN * 256 * 4;
    __hip_bfloat16* kbuf = (__hip_bfloat16*)p; p += (size_t)BN * 256 * 2;
    __hip_bfloat16* vbuf = (__hip_bfloat16*)p; p += (size_t)BN * 256 * 2;
    float*          sbuf = (float*)p;          p += (size_t)BN * DD * 4;
    __hip_bfloat16* xb   = (__hip_bfloat16*)p; p += (size_t)BN * DD * 2;
    __hip_bfloat16* Wt1  = (__hip_bfloat16*)p; p += (size_t)512 * DD * 2;
    __hip_bfloat16* Wt2  = (__hip_bfloat16*)p; p += (size_t)896 * DD * 2;
    int2*           csrb = (int2*)p;           p += (size_t)BN * CAP * 8;

    build_csr<<<BB * (NN / TD), 256, 0, stream>>>(A, edge, csrb);
    prep_weights<<<512, 128, 0, stream>>>(Wq[1], Wk[1], Wv[1], Ws[1], Wt1, DD);
    prep_weights<<<896, 128, 0, stream>>>(Wq[2], Wk[2], Wv[2], Ws[2], Wt2, 2 * DD);

    const int appL[7] = {0, 1, 2, 1, 2, 1, 2};

    for (int a = 0; a < 7; a++) {
        int l = appL[a];
        if (l == 0) {
            proj_l0<<<dim3(BN / 16, 4), 128, 0, stream>>>(node, Wq[0], Wk[0], Wv[0], Ws[0],
                                                          qbuf, kbuf, vbuf, sbuf);
        } else if (l == 1) {
            proj_mfma<DD><<<dim3(BN / 64, 8), 256, 0, stream>>>(xb, Wt1, qbuf, kbuf, vbuf, sbuf);
        } else {
            proj_mfma<2 * DD><<<dim3(BN / 64, 14), 256, 0, stream>>>(xb, Wt2, qbuf, kbuf, vbuf, sbuf);
        }
        if (l == 2) {
            if (a == 6)
                attn_kernel<2, true, false, false><<<BN, 256, 0, stream>>>(
                    qbuf, kbuf, vbuf, sbuf, csrb, We[l], d_out);
            else
                attn_kernel<2, true, false, true><<<BN, 256, 0, stream>>>(
                    qbuf, kbuf, vbuf, sbuf, csrb, We[l], xb);
        } else {
            attn_kernel<1, false, true, true><<<BN, 256, 0, stream>>>(
                qbuf, kbuf, vbuf, sbuf, csrb, We[l], xb);
        }
    }
}

// Round 9
// 439.375 us; speedup vs baseline: 1.0036x; 1.0036x over previous
//
#include <hip/hip_runtime.h>
#include <hip/hip_bf16.h>
#include <hip/hip_fp16.h>

#define BB 2
#define NN 2048
#define DD 128
#define BN (BB*NN)
#define CAP 128
#define TD 16
#define INV_SQRT_D 0.08838834764831845f

typedef __attribute__((ext_vector_type(8))) short short8;
typedef __attribute__((ext_vector_type(4))) float f32x4;

__device__ __forceinline__ float bf2f(short u) {
    union { unsigned int i; float f; } t;
    t.i = ((unsigned int)(unsigned short)u) << 16;
    return t.f;
}

// ---------------------------------------------------------------------------
// LDS-tiled CSR build of e_t[b,dst,src] = edge[b,src,dst]*A[b,src,dst].
// Packed u32 per slot: (global_src_row << 16) | fp16_bits(ee).
// FULL CAP slots per row; pads = 0 (ee==0 is the validity mask: real ee>=0.1).
// ---------------------------------------------------------------------------
__global__ __launch_bounds__(256) void build_csr(
    const float* __restrict__ A,
    const float* __restrict__ edge,
    unsigned* __restrict__ csr)
{
    __shared__ int   cnt[TD];
    __shared__ int   csh[TD][CAP];
    __shared__ float esh[TD][CAP];

    int bid  = blockIdx.x;
    int b    = bid / (NN / TD);
    int dst0 = (bid % (NN / TD)) * TD;
    int tid  = threadIdx.x;

    if (tid < TD) cnt[tid] = 0;
    __syncthreads();

    int srcOff = tid >> 2;
    int dOff   = (tid & 3) * 4;
    const size_t base = (size_t)b * NN * NN + dst0 + dOff;

#pragma unroll 2
    for (int s0 = 0; s0 < NN; s0 += 64) {
        int src = s0 + srcOff;
        float4 a4 = *(const float4*)&A[base + (size_t)src * NN];
        float4 e4 = *(const float4*)&edge[base + (size_t)src * NN];
        int gsrc = b * NN + src;
        float av[4] = {a4.x, a4.y, a4.z, a4.w};
        float ev[4] = {e4.x, e4.y, e4.z, e4.w};
#pragma unroll
        for (int u = 0; u < 4; u++) {
            if (av[u] != 0.f) {
                int d = dOff + u;
                int slot = atomicAdd(&cnt[d], 1);
                if (slot < CAP) { csh[d][slot] = gsrc; esh[d][slot] = ev[u] * av[u]; }
            }
        }
    }
    __syncthreads();

    for (int idx = tid; idx < TD * CAP; idx += 256) {
        int d = idx / CAP, i = idx % CAP;
        int c = min(cnt[d], CAP);
        unsigned val = 0u;
        if (i < c)
            val = ((unsigned)csh[d][i] << 16)
                | (unsigned)__half_as_ushort(__float2half_rn(esh[d][i]));
        csr[(size_t)(b * NN + dst0 + d) * CAP + i] = val;
    }
}

// ---------------------------------------------------------------------------
// Weight prep: Wt[n][k] = W*[k][n] as bf16, cols concat [q | k | v | skip].
// ---------------------------------------------------------------------------
__global__ __launch_bounds__(128) void prep_weights(
    const float* __restrict__ Wq, const float* __restrict__ Wk,
    const float* __restrict__ Wv, const float* __restrict__ Ws,
    __hip_bfloat16* __restrict__ Wt, int HD)
{
    int n = blockIdx.x;
    int t = threadIdx.x;
    const float* src; int ld; int col;
    if      (n < HD)     { src = Wq; col = n;          ld = HD; }
    else if (n < 2*HD)   { src = Wk; col = n - HD;     ld = HD; }
    else if (n < 3*HD)   { src = Wv; col = n - 2*HD;   ld = HD; }
    else                 { src = Ws; col = n - 3*HD;   ld = DD; }
    Wt[(size_t)n * DD + t] = __float2bfloat16(src[(size_t)t * ld + col]);
}

// ---------------------------------------------------------------------------
// Layer-0 projection (FIN=1, rank-1). q/skip fp32; k/v bf16.
// ---------------------------------------------------------------------------
__global__ __launch_bounds__(128) void proj_l0(
    const float* __restrict__ x,
    const float* __restrict__ Wq, const float* __restrict__ Wk,
    const float* __restrict__ Wv, const float* __restrict__ Ws,
    float* __restrict__ q, __hip_bfloat16* __restrict__ kb,
    __hip_bfloat16* __restrict__ vb, float* __restrict__ skip)
{
    __shared__ float xs[16];
    int row0 = blockIdx.x * 16;
    int col  = blockIdx.y * 128 + threadIdx.x;
    if (threadIdx.x < 16) xs[threadIdx.x] = x[row0 + threadIdx.x];
    __syncthreads();

    if (col < DD) {
        float wf = Wq[col];
#pragma unroll
        for (int r = 0; r < 16; r++) q[(size_t)(row0 + r) * DD + col] = xs[r] * wf;
    } else if (col < 2*DD) {
        float wf = Wk[col - DD];
#pragma unroll
        for (int r = 0; r < 16; r++) kb[(size_t)(row0 + r) * DD + col - DD] = __float2bfloat16(xs[r] * wf);
    } else if (col < 3*DD) {
        float wf = Wv[col - 2*DD];
#pragma unroll
        for (int r = 0; r < 16; r++) vb[(size_t)(row0 + r) * DD + col - 2*DD] = __float2bfloat16(xs[r] * wf);
    } else {
        float wf = Ws[col - 3*DD];
#pragma unroll
        for (int r = 0; r < 16; r++) skip[(size_t)(row0 + r) * DD + col - 3*DD] = xs[r] * wf;
    }
}

// ---------------------------------------------------------------------------
// MFMA bf16 projection. q/skip fp32 out; k/v bf16 out.
// ---------------------------------------------------------------------------
template<int HD>
__global__ __launch_bounds__(256) void proj_mfma(
    const __hip_bfloat16* __restrict__ xb,
    const __hip_bfloat16* __restrict__ Wt,
    float* __restrict__ q, __hip_bfloat16* __restrict__ kb,
    __hip_bfloat16* __restrict__ vb, float* __restrict__ skip)
{
    int wid  = threadIdx.x >> 6, lane = threadIdx.x & 63;
    int row0 = blockIdx.x * 64 + wid * 16;
    int n0   = blockIdx.y * 64;
    int m    = lane & 15, quad = lane >> 4;

    f32x4 acc[4] = {f32x4{0,0,0,0}, f32x4{0,0,0,0}, f32x4{0,0,0,0}, f32x4{0,0,0,0}};
    const short8* ap = (const short8*)&xb[(size_t)(row0 + m) * DD + quad * 8];
#pragma unroll
    for (int ks = 0; ks < 4; ks++) {
        short8 a = ap[ks * 4];
#pragma unroll
        for (int t = 0; t < 4; t++) {
            const short8* bp = (const short8*)&Wt[(size_t)(n0 + t * 16 + m) * DD + ks * 32 + quad * 8];
            acc[t] = __builtin_amdgcn_mfma_f32_16x16x32_bf16(a, *bp, acc[t], 0, 0, 0);
        }
    }

    if (n0 < HD) {
        int lc0 = n0;
#pragma unroll
        for (int t = 0; t < 4; t++)
#pragma unroll
            for (int r = 0; r < 4; r++)
                q[(size_t)(row0 + quad * 4 + r) * HD + lc0 + t * 16 + m] = acc[t][r];
    } else if (n0 < 2 * HD) {
        int lc0 = n0 - HD;
#pragma unroll
        for (int t = 0; t < 4; t++)
#pragma unroll
            for (int r = 0; r < 4; r++)
                kb[(size_t)(row0 + quad * 4 + r) * HD + lc0 + t * 16 + m] = __float2bfloat16(acc[t][r]);
    } else if (n0 < 3 * HD) {
        int lc0 = n0 - 2 * HD;
#pragma unroll
        for (int t = 0; t < 4; t++)
#pragma unroll
            for (int r = 0; r < 4; r++)
                vb[(size_t)(row0 + quad * 4 + r) * HD + lc0 + t * 16 + m] = __float2bfloat16(acc[t][r]);
    } else {
        int lc0 = n0 - 3 * HD;
#pragma unroll
        for (int t = 0; t < 4; t++)
#pragma unroll
            for (int r = 0; r < 4; r++)
                skip[(size_t)(row0 + quad * 4 + r) * DD + lc0 + t * 16 + m] = acc[t][r];
    }
}

// ---------------------------------------------------------------------------
// Sparse attention v5: static stream + batch->XCD swizzle + exact L2 warm.
// blockIdx g: xcd=g&7, batch=(g>>2)&1, dst i=(g>>3)*4+(g&3).
// XCDs 0-3 serve batch 0, 4-7 batch 1 -> each XCD only fills its batch's k/v.
// Each block additionally streams its 1/512 slice of the batch k/v (dense)
// to convert demand-miss fills into streaming fills.
// ---------------------------------------------------------------------------
template<int H, bool MEANH, bool LNRELU, bool OUTBF>
__global__ __launch_bounds__(256, 3) void attn_kernel(
    const float* __restrict__ q, const __hip_bfloat16* __restrict__ kb,
    const __hip_bfloat16* __restrict__ vb, const float* __restrict__ skip,
    const unsigned* __restrict__ csr, const float* __restrict__ We,
    void* __restrict__ outv)
{
    const int HD = H * DD;
    constexpr int UNR = (H == 1) ? 4 : 2;
    int tid  = threadIdx.x;
    int wid  = tid >> 6;
    int lane = tid & 63;
    int g    = blockIdx.x;
    int b    = (g >> 2) & 1;
    int sl   = g >> 3;
    int row  = b * NN + sl * 4 + (g & 3);
    int sub  = lane >> 3;
    int s    = lane & 7;

    __shared__ float red[4][H][8 * 20];     // stride-20 swizzle: conflict-free
    __shared__ float lred[4][H], ewred[4][H];

    // ---- L2 warm: this block's exact 1/512 slice of the batch's k/v ----
    {
        const int SB = NN * HD * 2 / 512;        // bytes per block per buffer
        int soff = tid * 16;
        if (soff < SB) {
            size_t base = (size_t)b * NN * HD * 2 + (size_t)sl * SB + soff;
            f32x4 tk = *(const f32x4*)((const char*)kb + base);
            f32x4 tv = *(const f32x4*)((const char*)vb + base);
            float w = tk[0]+tk[1]+tk[2]+tk[3]+tv[0]+tv[1]+tv[2]+tv[3];
            asm volatile("" :: "v"(w));
        }
    }

    // CSR slots for this wave's 4 groups (packed u32, no predicates)
    int jb[4]; float eb[4];
#pragma unroll
    for (int i = 0; i < 4; i++) {
        unsigned ce = csr[(size_t)row * CAP + i * 32 + wid * 8 + sub];
        jb[i] = (int)(ce >> 16);
        eb[i] = __half2float(__ushort_as_half((unsigned short)(ce & 0xffffu)));
    }

    // q fragment (16 ch/lane, dep on s only) + qe[h] = q . We[h]
    float qh[H][16];
    float qeI[H];
#pragma unroll
    for (int h = 0; h < H; h++) {
        const float* qp = &q[(size_t)row * HD + h * DD + s * 16];
        const float* wp = &We[h * DD + s * 16];
        float pe = 0.f;
#pragma unroll
        for (int t = 0; t < 16; t++) { qh[h][t] = qp[t]; pe += qp[t] * wp[t]; }
        pe += __shfl_xor(pe, 1); pe += __shfl_xor(pe, 2); pe += __shfl_xor(pe, 4);
        qeI[h] = pe * INV_SQRT_D;
    }

    float l_acc[H], ew_acc[H], acc[H][16];
#pragma unroll
    for (int h = 0; h < H; h++) {
        l_acc[h] = 0.f; ew_acc[h] = 0.f;
#pragma unroll
        for (int t = 0; t < 16; t++) acc[h][t] = 0.f;
    }

#pragma unroll
    for (int r0 = 0; r0 < 4; r0 += UNR) {
        short8 kf[UNR][H][2], vf[UNR][H][2];
#pragma unroll
        for (int u = 0; u < UNR; u++) {
            int j = jb[r0 + u];
#pragma unroll
            for (int h = 0; h < H; h++) {
                const short8* kp = (const short8*)&kb[(size_t)j * HD + h * DD + s * 16];
                const short8* vp = (const short8*)&vb[(size_t)j * HD + h * DD + s * 16];
                kf[u][h][0] = kp[0]; kf[u][h][1] = kp[1];
                vf[u][h][0] = vp[0]; vf[u][h][1] = vp[1];
            }
        }
#pragma unroll
        for (int u = 0; u < UNR; u++) {
            float ee = eb[r0 + u];
#pragma unroll
            for (int h = 0; h < H; h++) {
                float p = 0.f;
#pragma unroll
                for (int t = 0; t < 8; t++) p += qh[h][t]     * bf2f(kf[u][h][0][t]);
#pragma unroll
                for (int t = 0; t < 8; t++) p += qh[h][8 + t] * bf2f(kf[u][h][1][t]);
                p += __shfl_xor(p, 1); p += __shfl_xor(p, 2); p += __shfl_xor(p, 4);
                float sc = p * INV_SQRT_D + qeI[h] * ee;
                float a  = (ee > 0.f) ? __expf(fminf(sc, 60.f)) : 0.f;
                l_acc[h]  += a;
                ew_acc[h] += a * ee;
#pragma unroll
                for (int t = 0; t < 8; t++) acc[h][t]     += a * bf2f(vf[u][h][0][t]);
#pragma unroll
                for (int t = 0; t < 8; t++) acc[h][8 + t] += a * bf2f(vf[u][h][1][t]);
            }
        }
    }

    // one-time butterfly over sub bits {8,16,32}
#pragma unroll
    for (int h = 0; h < H; h++) {
#pragma unroll
        for (int t = 0; t < 16; t++) {
            float x = acc[h][t];
            x += __shfl_xor(x, 8); x += __shfl_xor(x, 16); x += __shfl_xor(x, 32);
            acc[h][t] = x;
        }
        float l = l_acc[h];
        l += __shfl_xor(l, 8); l += __shfl_xor(l, 16); l += __shfl_xor(l, 32);
        l_acc[h] = l;
        float ew = ew_acc[h];
        ew += __shfl_xor(ew, 8); ew += __shfl_xor(ew, 16); ew += __shfl_xor(ew, 32);
        ew_acc[h] = ew;
    }

    // per-wave partials -> LDS (stride-20: banks 0,20,8,28,16,4,24,12)
    if (lane < 8) {
#pragma unroll
        for (int h = 0; h < H; h++)
#pragma unroll
            for (int t4 = 0; t4 < 4; t4++) {
                f32x4 v4 = { acc[h][t4*4], acc[h][t4*4+1], acc[h][t4*4+2], acc[h][t4*4+3] };
                *(f32x4*)&red[wid][h][lane * 20 + t4 * 4] = v4;
            }
    }
    if (lane == 0) {
#pragma unroll
        for (int h = 0; h < H; h++) { lred[wid][h] = l_acc[h]; ewred[wid][h] = ew_acc[h]; }
    }
    __syncthreads();

    // epilogue on wave 0 (2 ch/lane)
    if (wid == 0) {
        int c0 = lane * 2;
        int ri = (c0 >> 4) * 20 + (c0 & 15);
        float rh[H][2];
#pragma unroll
        for (int h = 0; h < H; h++) {
            float a0 = 0.f, a1 = 0.f, l = 0.f, ew = 0.f;
#pragma unroll
            for (int w = 0; w < 4; w++) {
                a0 += red[w][h][ri];
                a1 += red[w][h][ri + 1];
                l  += lred[w][h];
                ew += ewred[w][h];
            }
            float invZ = (l > 0.f) ? 1.f / l : 0.f;
            rh[h][0] = (a0 + ew * We[h * DD + c0])     * invZ;
            rh[h][1] = (a1 + ew * We[h * DD + c0 + 1]) * invZ;
        }
        float r0, r1;
        if constexpr (MEANH) {
            r0 = 0.5f * (rh[0][0] + rh[H - 1][0]);
            r1 = 0.5f * (rh[0][1] + rh[H - 1][1]);
        } else {
            r0 = rh[0][0]; r1 = rh[0][1];
        }
        float2 sk = *(const float2*)&skip[(size_t)row * DD + c0];
        r0 += sk.x; r1 += sk.y;

        if constexpr (LNRELU) {
            float sum = r0 + r1, sq = r0 * r0 + r1 * r1;
#pragma unroll
            for (int off = 32; off; off >>= 1) { sum += __shfl_xor(sum, off); sq += __shfl_xor(sq, off); }
            float mu  = sum * (1.f / DD);
            float var = sq * (1.f / DD) - mu * mu;
            float rs  = rsqrtf(var + 1e-5f);
            r0 = fmaxf((r0 - mu) * rs, 0.f);
            r1 = fmaxf((r1 - mu) * rs, 0.f);
        }

        if constexpr (OUTBF) {
            __hip_bfloat16* ob = (__hip_bfloat16*)outv;
            __hip_bfloat162 o;
            o.x = __float2bfloat16(r0);
            o.y = __float2bfloat16(r1);
            *(__hip_bfloat162*)&ob[(size_t)row * DD + c0] = o;
        } else {
            float2 res; res.x = r0; res.y = r1;
            *(float2*)&((float*)outv)[(size_t)row * DD + c0] = res;
        }
    }
}

// ---------------------------------------------------------------------------
extern "C" void kernel_launch(void* const* d_in, const int* in_sizes, int n_in,
                              void* d_out, int out_size, void* d_ws, size_t ws_size,
                              hipStream_t stream)
{
    const float* node = (const float*)d_in[0];
    const float* edge = (const float*)d_in[1];
    const float* A    = (const float*)d_in[2];
    const float* Wq[3] = {(const float*)d_in[3],  (const float*)d_in[8],  (const float*)d_in[13]};
    const float* Wk[3] = {(const float*)d_in[4],  (const float*)d_in[9],  (const float*)d_in[14]};
    const float* Wv[3] = {(const float*)d_in[5],  (const float*)d_in[10], (const float*)d_in[15]};
    const float* We[3] = {(const float*)d_in[6],  (const float*)d_in[11], (const float*)d_in[16]};
    const float* Ws[3] = {(const float*)d_in[7],  (const float*)d_in[12], (const float*)d_in[17]};

    // workspace carve
    char* p = (char*)d_ws;
    float*          qbuf = (float*)p;          p += (size_t)BN * 256 * 4;
    __hip_bfloat16* kbuf = (__hip_bfloat16*)p; p += (size_t)BN * 256 * 2;
    __hip_bfloat16* vbuf = (__hip_bfloat16*)p; p += (size_t)BN * 256 * 2;
    float*          sbuf = (float*)p;          p += (size_t)BN * DD * 4;
    __hip_bfloat16* xb   = (__hip_bfloat16*)p; p += (size_t)BN * DD * 2;
    __hip_bfloat16* Wt1  = (__hip_bfloat16*)p; p += (size_t)512 * DD * 2;
    __hip_bfloat16* Wt2  = (__hip_bfloat16*)p; p += (size_t)896 * DD * 2;
    unsigned*       csrb = (unsigned*)p;       p += (size_t)BN * CAP * 4;

    build_csr<<<BB * (NN / TD), 256, 0, stream>>>(A, edge, csrb);
    prep_weights<<<512, 128, 0, stream>>>(Wq[1], Wk[1], Wv[1], Ws[1], Wt1, DD);
    prep_weights<<<896, 128, 0, stream>>>(Wq[2], Wk[2], Wv[2], Ws[2], Wt2, 2 * DD);

    const int appL[7] = {0, 1, 2, 1, 2, 1, 2};

    for (int a = 0; a < 7; a++) {
        int l = appL[a];
        if (l == 0) {
            proj_l0<<<dim3(BN / 16, 4), 128, 0, stream>>>(node, Wq[0], Wk[0], Wv[0], Ws[0],
                                                          qbuf, kbuf, vbuf, sbuf);
        } else if (l == 1) {
            proj_mfma<DD><<<dim3(BN / 64, 8), 256, 0, stream>>>(xb, Wt1, qbuf, kbuf, vbuf, sbuf);
        } else {
            proj_mfma<2 * DD><<<dim3(BN / 64, 14), 256, 0, stream>>>(xb, Wt2, qbuf, kbuf, vbuf, sbuf);
        }
        if (l == 2) {
            if (a == 6)
                attn_kernel<2, true, false, false><<<BN, 256, 0, stream>>>(
                    qbuf, kbuf, vbuf, sbuf, csrb, We[l], d_out);
            else
                attn_kernel<2, true, false, true><<<BN, 256, 0, stream>>>(
                    qbuf, kbuf, vbuf, sbuf, csrb, We[l], xb);
        } else {
            attn_kernel<1, false, true, true><<<BN, 256, 0, stream>>>(
                qbuf, kbuf, vbuf, sbuf, csrb, We[l], xb);
        }
    }
}